// Round 1
// baseline (943.652 us; speedup 1.0000x reference)
//
#include <hip/hip_runtime.h>
#include <cstdint>
#include <cstddef>

#define NB 2
#define NTOK 12096
#define TOKS (NB * NTOK)   // 24192
#define DIMC 384
#define NHEADS 6
#define CHD 64
#define NLEV 3
#define NPTS 4

// level geometry: L0 96x96 (9216), L1 48x48 (2304), L2 24x24 (576)
__device__ __forceinline__ float wave_reduce_add(float v) {
#pragma unroll
  for (int o = 32; o > 0; o >>= 1) v += __shfl_xor(v, o, 64);
  return v;
}

// ---------------------------------------------------------------------------
// K1: q = query (+feat on middle level); qn = LN(q,w1,b1); fn = LN(q,w2,b2);
//     aq = LN(qn,w3,b3); af = LN(fn,w4,b4). One wave per token, 6 elems/lane.
// ---------------------------------------------------------------------------
__global__ __launch_bounds__(256) void fused_ln3(
    const float* __restrict__ query, const float* __restrict__ feat,
    const float* __restrict__ w1, const float* __restrict__ b1,
    const float* __restrict__ w2, const float* __restrict__ b2,
    const float* __restrict__ w3, const float* __restrict__ b3,
    const float* __restrict__ w4, const float* __restrict__ b4,
    float* __restrict__ qn, float* __restrict__ aq, float* __restrict__ af) {
  int wid = (blockIdx.x * blockDim.x + threadIdx.x) >> 6;
  if (wid >= TOKS) return;
  int lane = threadIdx.x & 63;
  int bb = wid / NTOK;
  int nq = wid - bb * NTOK;

  float x[6];
  const float* qp = query + (size_t)wid * DIMC + lane;
#pragma unroll
  for (int i = 0; i < 6; ++i) x[i] = qp[64 * i];
  if (nq >= 9216 && nq < 11520) {
    const float* fp = feat + ((size_t)bb * 2304 + (nq - 9216)) * DIMC + lane;
#pragma unroll
    for (int i = 0; i < 6; ++i) x[i] += fp[64 * i];
  }

  float s = 0.f, ss = 0.f;
#pragma unroll
  for (int i = 0; i < 6; ++i) { s += x[i]; ss += x[i] * x[i]; }
  s = wave_reduce_add(s); ss = wave_reduce_add(ss);
  float mean = s * (1.f / DIMC);
  float var = ss * (1.f / DIMC) - mean * mean;
  float rs = rsqrtf(var + 1e-6f);

  float qv[6], fv[6];
  float* qnp = qn + (size_t)wid * DIMC + lane;
#pragma unroll
  for (int i = 0; i < 6; ++i) {
    int e = lane + 64 * i;
    float xh = (x[i] - mean) * rs;
    qv[i] = xh * w1[e] + b1[e];
    fv[i] = xh * w2[e] + b2[e];
    qnp[64 * i] = qv[i];
  }

  // aq = LN(qv)
  s = 0.f; ss = 0.f;
#pragma unroll
  for (int i = 0; i < 6; ++i) { s += qv[i]; ss += qv[i] * qv[i]; }
  s = wave_reduce_add(s); ss = wave_reduce_add(ss);
  float m2 = s * (1.f / DIMC);
  float rs2 = rsqrtf(ss * (1.f / DIMC) - m2 * m2 + 1e-6f);
  float* aqp = aq + (size_t)wid * DIMC + lane;
#pragma unroll
  for (int i = 0; i < 6; ++i) {
    int e = lane + 64 * i;
    aqp[64 * i] = (qv[i] - m2) * rs2 * w3[e] + b3[e];
  }

  // af = LN(fv)
  s = 0.f; ss = 0.f;
#pragma unroll
  for (int i = 0; i < 6; ++i) { s += fv[i]; ss += fv[i] * fv[i]; }
  s = wave_reduce_add(s); ss = wave_reduce_add(ss);
  float m3 = s * (1.f / DIMC);
  float rs3 = rsqrtf(ss * (1.f / DIMC) - m3 * m3 + 1e-6f);
  float* afp = af + (size_t)wid * DIMC + lane;
#pragma unroll
  for (int i = 0; i < 6; ++i) {
    int e = lane + 64 * i;
    afp[64 * i] = (fv[i] - m3) * rs3 * w4[e] + b4[e];
  }
}

// ---------------------------------------------------------------------------
// Plain single-LN (ffn_norm on `out`)
// ---------------------------------------------------------------------------
__global__ __launch_bounds__(256) void ln_kernel(
    const float* __restrict__ x, const float* __restrict__ w,
    const float* __restrict__ b, float* __restrict__ y) {
  int wid = (blockIdx.x * blockDim.x + threadIdx.x) >> 6;
  if (wid >= TOKS) return;
  int lane = threadIdx.x & 63;
  float v[6];
  const float* xp = x + (size_t)wid * DIMC + lane;
#pragma unroll
  for (int i = 0; i < 6; ++i) v[i] = xp[64 * i];
  float s = 0.f, ss = 0.f;
#pragma unroll
  for (int i = 0; i < 6; ++i) { s += v[i]; ss += v[i] * v[i]; }
  s = wave_reduce_add(s); ss = wave_reduce_add(ss);
  float mean = s * (1.f / DIMC);
  float rs = rsqrtf(ss * (1.f / DIMC) - mean * mean + 1e-6f);
  float* yp = y + (size_t)wid * DIMC + lane;
#pragma unroll
  for (int i = 0; i < 6; ++i) {
    int e = lane + 64 * i;
    yp[64 * i] = (v[i] - mean) * rs * w[e] + b[e];
  }
}

// ---------------------------------------------------------------------------
// fp32 tiled GEMM: C[M x Nout] = A[M x K] @ W[K x Nout] + bias
// EPI 0: bias only; 1: + R (residual, stride Nout); 2: accumulate into C.
// Grid: (ceil(Nout/64), M/64); M multiple of 64, K multiple of 32.
// ---------------------------------------------------------------------------
template <int EPI>
__global__ __launch_bounds__(256) void gemm64(
    const float* __restrict__ A, const float* __restrict__ W,
    const float* __restrict__ bias, const float* __restrict__ R,
    float* __restrict__ C, int K, int Nout) {
  __shared__ float As[32][65];
  __shared__ float Ws[32][65];
  int tid = threadIdx.x;
  int tx = tid & 15, ty = tid >> 4;
  int m0 = blockIdx.y * 64, n0 = blockIdx.x * 64;
  float acc[4][4] = {};
  for (int k0 = 0; k0 < K; k0 += 32) {
#pragma unroll
    for (int i = 0; i < 8; ++i) {
      int e = tid + 256 * i;
      int m = e >> 5, k = e & 31;
      As[k][m] = A[(size_t)(m0 + m) * K + k0 + k];
    }
#pragma unroll
    for (int i = 0; i < 8; ++i) {
      int e = tid + 256 * i;
      int k = e >> 6, nn = e & 63;
      int nidx = n0 + nn;
      Ws[k][nn] = (nidx < Nout) ? W[(size_t)(k0 + k) * Nout + nidx] : 0.f;
    }
    __syncthreads();
#pragma unroll
    for (int kk = 0; kk < 32; ++kk) {
      float a[4], w[4];
#pragma unroll
      for (int i = 0; i < 4; ++i) a[i] = As[kk][ty + 16 * i];
#pragma unroll
      for (int j = 0; j < 4; ++j) w[j] = Ws[kk][tx + 16 * j];
#pragma unroll
      for (int i = 0; i < 4; ++i)
#pragma unroll
        for (int j = 0; j < 4; ++j) acc[i][j] = fmaf(a[i], w[j], acc[i][j]);
    }
    __syncthreads();
  }
#pragma unroll
  for (int i = 0; i < 4; ++i) {
    int m = m0 + ty + 16 * i;
#pragma unroll
    for (int j = 0; j < 4; ++j) {
      int nidx = n0 + tx + 16 * j;
      if (nidx < Nout) {
        size_t o = (size_t)m * Nout + nidx;
        float v = acc[i][j] + bias[nidx];
        if (EPI == 1) v += R[o];
        if (EPI == 2) v += C[o];
        C[o] = v;
      }
    }
  }
}

// ---------------------------------------------------------------------------
// Deformable sampling. One wave per (b, n, head); lane = channel (64).
// samp[b,n,h,c] = sum_{l,p} softmax(att)[l,p] * bilinear(value_l)[c]
// ---------------------------------------------------------------------------
__global__ __launch_bounds__(256) void msdeform_sample(
    const float* __restrict__ value, const float* __restrict__ off,
    const float* __restrict__ attl, float* __restrict__ samp) {
  int wid = (blockIdx.x * blockDim.x + threadIdx.x) >> 6;
  if (wid >= TOKS * NHEADS) return;
  int lane = threadIdx.x & 63;
  int h = wid % NHEADS;
  int t = wid / NHEADS;          // b*NTOK + nq
  int b = t / NTOK;
  int nq = t - b * NTOK;

  // reference point from the query's own level grid
  int pos, Hq, Wq;
  if (nq < 9216)       { pos = nq;         Hq = 96; Wq = 96; }
  else if (nq < 11520) { pos = nq - 9216;  Hq = 48; Wq = 48; }
  else                 { pos = nq - 11520; Hq = 24; Wq = 24; }
  int iq = pos / Wq, jq = pos - iq * Wq;
  float refx = (jq + 0.5f) / (float)Wq;
  float refy = (iq + 0.5f) / (float)Hq;

  // softmax over 12 logits (redundant per lane; cheap)
  const float* lg = attl + ((size_t)t * NHEADS + h) * 12;
  float e[12];
  float mx = -1e30f;
#pragma unroll
  for (int i = 0; i < 12; ++i) mx = fmaxf(mx, lg[i]);
  float sden = 0.f;
#pragma unroll
  for (int i = 0; i < 12; ++i) { e[i] = expf(lg[i] - mx); sden += e[i]; }
  float inv = 1.f / sden;

  const float* of = off + ((size_t)t * NHEADS + h) * 24;
  const float* vb = value + (size_t)b * NTOK * DIMC;

  const int Hls[3] = {96, 48, 24};
  const int Sts[3] = {0, 9216, 11520};

  float acc = 0.f;
#pragma unroll
  for (int l = 0; l < NLEV; ++l) {
    const int Hl = Hls[l], Wl = Hls[l], st = Sts[l];
#pragma unroll
    for (int p = 0; p < NPTS; ++p) {
      float ox = of[(l * 4 + p) * 2 + 0];
      float oy = of[(l * 4 + p) * 2 + 1];
      float xx = (refx + ox / (float)Wl) * (float)Wl - 0.5f;
      float yy = (refy + oy / (float)Hl) * (float)Hl - 0.5f;
      float x0f = floorf(xx), y0f = floorf(yy);
      int x0 = (int)x0f, y0 = (int)y0f;
      float wx = xx - x0f, wy = yy - y0f;
      float aw = e[l * 4 + p] * inv;

      auto tap = [&](int ty_, int tx_) -> float {
        if (ty_ < 0 || ty_ >= Hl || tx_ < 0 || tx_ >= Wl) return 0.f;
        return vb[((size_t)(st + ty_ * Wl + tx_) * NHEADS + h) * CHD + lane];
      };
      float v00 = tap(y0, x0), v01 = tap(y0, x0 + 1);
      float v10 = tap(y0 + 1, x0), v11 = tap(y0 + 1, x0 + 1);
      float bl = (v00 * (1.f - wx) + v01 * wx) * (1.f - wy) +
                 (v10 * (1.f - wx) + v11 * wx) * wy;
      acc += aw * bl;
    }
  }
  samp[((size_t)t * NHEADS + h) * CHD + lane] = acc;
}

// ---------------------------------------------------------------------------
// Depthwise 3x3 conv per level (SAME, zero pad) + bias + exact GELU.
// One thread per (token, channel); channels=96 so reads are coalesced.
// ---------------------------------------------------------------------------
__global__ __launch_bounds__(256) void dwconv_gelu(
    const float* __restrict__ x, const float* __restrict__ w,
    const float* __restrict__ bias, float* __restrict__ y) {
  int id = blockIdx.x * blockDim.x + threadIdx.x;
  if (id >= TOKS * 96) return;
  int ch = id % 96;
  int tn = id / 96;
  int b = tn / NTOK, nq = tn - b * NTOK;

  int pos, Hl, Wl, st;
  if (nq < 9216)       { pos = nq;         Hl = 96; Wl = 96; st = 0; }
  else if (nq < 11520) { pos = nq - 9216;  Hl = 48; Wl = 48; st = 9216; }
  else                 { pos = nq - 11520; Hl = 24; Wl = 24; st = 11520; }
  int i = pos / Wl, j = pos - i * Wl;

  float acc = bias[ch];
#pragma unroll
  for (int di = 0; di < 3; ++di) {
#pragma unroll
    for (int dj = 0; dj < 3; ++dj) {
      int ii = i + di - 1, jj = j + dj - 1;
      if (ii >= 0 && ii < Hl && jj >= 0 && jj < Wl) {
        acc += x[((size_t)(b * NTOK + st + ii * Wl + jj)) * 96 + ch] *
               w[(di * 3 + dj) * 96 + ch];
      }
    }
  }
  float g = 0.5f * acc * (1.f + erff(acc * 0.70710678118654752440f));
  y[id] = g;
}

// ---------------------------------------------------------------------------
extern "C" void kernel_launch(void* const* d_in, const int* in_sizes, int n_in,
                              void* d_out, int out_size, void* d_ws, size_t ws_size,
                              hipStream_t stream) {
  const float* query = (const float*)d_in[0];
  // d_in[1] = reference_points (unused by the reference computation)
  const float* feat   = (const float*)d_in[2];
  // d_in[3] spatial_shapes, d_in[4] level_start_index, d_in[5] H, d_in[6] W (constants)
  const float* cti_qw = (const float*)d_in[7];
  const float* cti_qb = (const float*)d_in[8];
  const float* cti_fw = (const float*)d_in[9];
  const float* cti_fb = (const float*)d_in[10];
  const float* cf_qw  = (const float*)d_in[11];
  const float* cf_qb  = (const float*)d_in[12];
  const float* cf_fw  = (const float*)d_in[13];
  const float* cf_fb  = (const float*)d_in[14];
  const float* Wv     = (const float*)d_in[15];
  const float* bv     = (const float*)d_in[16];
  const float* Woff   = (const float*)d_in[17];
  const float* boff   = (const float*)d_in[18];
  const float* Watt   = (const float*)d_in[19];
  const float* batt   = (const float*)d_in[20];
  const float* Wo     = (const float*)d_in[21];
  const float* bo     = (const float*)d_in[22];
  const float* ffw    = (const float*)d_in[23];
  const float* ffb    = (const float*)d_in[24];
  const float* fc1w   = (const float*)d_in[25];
  const float* fc1b   = (const float*)d_in[26];
  const float* dww    = (const float*)d_in[27];
  const float* dwb    = (const float*)d_in[28];
  const float* fc2w   = (const float*)d_in[29];
  const float* fc2b   = (const float*)d_in[30];
  float* out = (float*)d_out;

  // workspace layout (fp32), with reuse
  float* qn   = (float*)d_ws;               // TOKS*384 (alive until Wout epilogue)
  float* aq   = qn  + (size_t)TOKS * DIMC;  // TOKS*384 (reused as ln_ffn)
  float* af   = aq  + (size_t)TOKS * DIMC;  // TOKS*384 (reused as sampled)
  float* val  = af  + (size_t)TOKS * DIMC;  // TOKS*384
  float* off  = val + (size_t)TOKS * DIMC;  // TOKS*144 (+attl region reused as h1,h2)
  float* attl = off + (size_t)TOKS * 144;   // TOKS*72
  float* samp = af;
  float* lnf  = aq;
  float* h1   = off;                        // TOKS*96
  float* h2   = off + (size_t)TOKS * 96;    // TOKS*96 (fits in 144+72 region)

  dim3 blk(256);

  fused_ln3<<<TOKS / 4, blk, 0, stream>>>(query, feat, cti_qw, cti_qb, cti_fw,
                                          cti_fb, cf_qw, cf_qb, cf_fw, cf_fb,
                                          qn, aq, af);

  gemm64<0><<<dim3(6, TOKS / 64), blk, 0, stream>>>(af, Wv, bv, nullptr, val, 384, 384);
  gemm64<0><<<dim3(3, TOKS / 64), blk, 0, stream>>>(aq, Woff, boff, nullptr, off, 384, 144);
  gemm64<0><<<dim3(2, TOKS / 64), blk, 0, stream>>>(aq, Watt, batt, nullptr, attl, 384, 72);

  msdeform_sample<<<(TOKS * NHEADS) / 4, blk, 0, stream>>>(val, off, attl, samp);

  // out = samp @ Wout + bout + qn
  gemm64<1><<<dim3(6, TOKS / 64), blk, 0, stream>>>(samp, Wo, bo, qn, out, 384, 384);

  ln_kernel<<<TOKS / 4, blk, 0, stream>>>(out, ffw, ffb, lnf);
  gemm64<0><<<dim3(2, TOKS / 64), blk, 0, stream>>>(lnf, fc1w, fc1b, nullptr, h1, 384, 96);
  dwconv_gelu<<<(TOKS * 96 + 255) / 256, blk, 0, stream>>>(h1, dww, dwb, h2);
  // out += h2 @ fc2 + fc2_b
  gemm64<2><<<dim3(6, TOKS / 64), blk, 0, stream>>>(h2, fc2w, fc2b, nullptr, out, 96, 384);
}

// Round 2
// 419.524 us; speedup vs baseline: 2.2493x; 2.2493x over previous
//
#include <hip/hip_runtime.h>
#include <hip/hip_bf16.h>
#include <cstdint>
#include <cstddef>

#define NB 2
#define NTOK 12096
#define TOKS (NB * NTOK)   // 24192
#define DIMC 384
#define NHEADS 6
#define CHD 64

typedef __attribute__((ext_vector_type(8))) __bf16 bf16x8;
typedef __attribute__((ext_vector_type(4))) float f32x4;

__device__ __forceinline__ float wave_reduce_add(float v) {
#pragma unroll
  for (int o = 32; o > 0; o >>= 1) v += __shfl_xor(v, o, 64);
  return v;
}

// ---------------------------------------------------------------------------
// Weight conversion: fp32 [K][N] -> bf16 transposed+padded [Np][K], plus
// concatenated/padded biases. One thread per (n,k) of the 384x384 domain.
// ---------------------------------------------------------------------------
__global__ __launch_bounds__(256) void convert_weights(
    const float* __restrict__ Wv, const float* __restrict__ Woff,
    const float* __restrict__ Watt, const float* __restrict__ Wo,
    const float* __restrict__ fc1, const float* __restrict__ fc2,
    const float* __restrict__ boff, const float* __restrict__ batt,
    const float* __restrict__ fc1b,
    __hip_bfloat16* __restrict__ Wvt, __hip_bfloat16* __restrict__ Wot,
    __hip_bfloat16* __restrict__ Wofat, __hip_bfloat16* __restrict__ fc1t,
    __hip_bfloat16* __restrict__ fc2t, float* __restrict__ bofat,
    float* __restrict__ fc1bp) {
  int id = blockIdx.x * 256 + threadIdx.x;
  if (id >= 384 * 384) return;
  int k = id % 384, n = id / 384;
  Wvt[(size_t)n * 384 + k] = __float2bfloat16(Wv[(size_t)k * 384 + n]);
  Wot[(size_t)n * 384 + k] = __float2bfloat16(Wo[(size_t)k * 384 + n]);
  if (n < 256) {
    float v = 0.f;
    if (n < 144) v = Woff[(size_t)k * 144 + n];
    else if (n < 216) v = Watt[(size_t)k * 72 + (n - 144)];
    Wofat[(size_t)n * 384 + k] = __float2bfloat16(v);
  }
  if (n < 128)
    fc1t[(size_t)n * 384 + k] = __float2bfloat16(n < 96 ? fc1[(size_t)k * 96 + n] : 0.f);
  if (k < 96)
    fc2t[(size_t)n * 96 + k] = __float2bfloat16(fc2[(size_t)k * 384 + n]);
  if (id < 256) bofat[id] = id < 144 ? boff[id] : (id < 216 ? batt[id - 144] : 0.f);
  if (id < 128) fc1bp[id] = id < 96 ? fc1b[id] : 0.f;
}

// ---------------------------------------------------------------------------
// K1: q = query (+feat on middle level); qn = LN(q)*w1+b1 (fp32);
// aq = LN(qn)*w3+b3 (bf16); af = LN(LN(q)*w2+b2)*w4+b4 (bf16).
// One wave per token.
// ---------------------------------------------------------------------------
__global__ __launch_bounds__(256) void fused_ln3(
    const float* __restrict__ query, const float* __restrict__ feat,
    const float* __restrict__ w1, const float* __restrict__ b1,
    const float* __restrict__ w2, const float* __restrict__ b2,
    const float* __restrict__ w3, const float* __restrict__ b3,
    const float* __restrict__ w4, const float* __restrict__ b4,
    float* __restrict__ qn, __hip_bfloat16* __restrict__ aq,
    __hip_bfloat16* __restrict__ af) {
  int wid = (blockIdx.x * blockDim.x + threadIdx.x) >> 6;
  if (wid >= TOKS) return;
  int lane = threadIdx.x & 63;
  int bb = wid / NTOK;
  int nq = wid - bb * NTOK;

  float x[6];
  const float* qp = query + (size_t)wid * DIMC + lane;
#pragma unroll
  for (int i = 0; i < 6; ++i) x[i] = qp[64 * i];
  if (nq >= 9216 && nq < 11520) {
    const float* fp = feat + ((size_t)bb * 2304 + (nq - 9216)) * DIMC + lane;
#pragma unroll
    for (int i = 0; i < 6; ++i) x[i] += fp[64 * i];
  }

  float s = 0.f, ss = 0.f;
#pragma unroll
  for (int i = 0; i < 6; ++i) { s += x[i]; ss += x[i] * x[i]; }
  s = wave_reduce_add(s); ss = wave_reduce_add(ss);
  float mean = s * (1.f / DIMC);
  float rs = rsqrtf(ss * (1.f / DIMC) - mean * mean + 1e-6f);

  float qv[6], fv[6];
  float* qnp = qn + (size_t)wid * DIMC + lane;
#pragma unroll
  for (int i = 0; i < 6; ++i) {
    int e = lane + 64 * i;
    float xh = (x[i] - mean) * rs;
    qv[i] = xh * w1[e] + b1[e];
    fv[i] = xh * w2[e] + b2[e];
    qnp[64 * i] = qv[i];
  }

  s = 0.f; ss = 0.f;
#pragma unroll
  for (int i = 0; i < 6; ++i) { s += qv[i]; ss += qv[i] * qv[i]; }
  s = wave_reduce_add(s); ss = wave_reduce_add(ss);
  float m2 = s * (1.f / DIMC);
  float rs2 = rsqrtf(ss * (1.f / DIMC) - m2 * m2 + 1e-6f);
  __hip_bfloat16* aqp = aq + (size_t)wid * DIMC + lane;
#pragma unroll
  for (int i = 0; i < 6; ++i) {
    int e = lane + 64 * i;
    aqp[64 * i] = __float2bfloat16((qv[i] - m2) * rs2 * w3[e] + b3[e]);
  }

  s = 0.f; ss = 0.f;
#pragma unroll
  for (int i = 0; i < 6; ++i) { s += fv[i]; ss += fv[i] * fv[i]; }
  s = wave_reduce_add(s); ss = wave_reduce_add(ss);
  float m3 = s * (1.f / DIMC);
  float rs3 = rsqrtf(ss * (1.f / DIMC) - m3 * m3 + 1e-6f);
  __hip_bfloat16* afp = af + (size_t)wid * DIMC + lane;
#pragma unroll
  for (int i = 0; i < 6; ++i) {
    int e = lane + 64 * i;
    afp[64 * i] = __float2bfloat16((fv[i] - m3) * rs3 * w4[e] + b4[e]);
  }
}

// ---------------------------------------------------------------------------
// ffn_norm: fp32 in -> bf16 out
// ---------------------------------------------------------------------------
__global__ __launch_bounds__(256) void ln_kernel(
    const float* __restrict__ x, const float* __restrict__ w,
    const float* __restrict__ b, __hip_bfloat16* __restrict__ y) {
  int wid = (blockIdx.x * blockDim.x + threadIdx.x) >> 6;
  if (wid >= TOKS) return;
  int lane = threadIdx.x & 63;
  float v[6];
  const float* xp = x + (size_t)wid * DIMC + lane;
#pragma unroll
  for (int i = 0; i < 6; ++i) v[i] = xp[64 * i];
  float s = 0.f, ss = 0.f;
#pragma unroll
  for (int i = 0; i < 6; ++i) { s += v[i]; ss += v[i] * v[i]; }
  s = wave_reduce_add(s); ss = wave_reduce_add(ss);
  float mean = s * (1.f / DIMC);
  float rs = rsqrtf(ss * (1.f / DIMC) - mean * mean + 1e-6f);
  __hip_bfloat16* yp = y + (size_t)wid * DIMC + lane;
#pragma unroll
  for (int i = 0; i < 6; ++i) {
    int e = lane + 64 * i;
    yp[64 * i] = __float2bfloat16((v[i] - mean) * rs * w[e] + b[e]);
  }
}

// ---------------------------------------------------------------------------
// bf16 MFMA GEMM: C[M x Np] = A[M x K](bf16) @ Wt[Np x K](bf16, transposed)
// 128x128 tile, 4 waves (2x2), each wave 64x64 = 4x4 16x16x32 fragments.
// EPI 0: +bias; 1: +bias+R; 2: +bias+=C.  OUTBF16: write bf16 instead of f32.
// ---------------------------------------------------------------------------
template <int EPI, int OUTBF16>
__global__ __launch_bounds__(256) void gemm_mfma(
    const __hip_bfloat16* __restrict__ A, const __hip_bfloat16* __restrict__ Wt,
    const float* __restrict__ bias, const float* __restrict__ R,
    void* __restrict__ Cv, int K, int Np) {
  __shared__ __align__(16) ushort As[128 * 32];
  __shared__ __align__(16) ushort Bs[128 * 32];
  const int tid = threadIdx.x;
  const int m0 = blockIdx.y * 128, n0 = blockIdx.x * 128;
  const int lane = tid & 63, wid = tid >> 6;
  const int wm = (wid >> 1) * 64, wn = (wid & 1) * 64;
  const int srow = tid >> 2, skb = tid & 3;
  const int rl = lane & 15, kb = lane >> 4;
  f32x4 acc[4][4] = {};

  for (int k0 = 0; k0 < K; k0 += 32) {
#pragma unroll
    for (int hh = 0; hh < 2; ++hh) {
      int r = srow + hh * 64;
      const ushort* ga = (const ushort*)A + (size_t)(m0 + r) * K + k0 + skb * 8;
      const ushort* gb = (const ushort*)Wt + (size_t)(n0 + r) * K + k0 + skb * 8;
      *(bf16x8*)&As[r * 32 + ((skb ^ (r & 3)) << 3)] = *(const bf16x8*)ga;
      *(bf16x8*)&Bs[r * 32 + ((skb ^ (r & 3)) << 3)] = *(const bf16x8*)gb;
    }
    __syncthreads();
    bf16x8 avf[4], bvf[4];
#pragma unroll
    for (int i = 0; i < 4; ++i) {
      int ra = wm + i * 16 + rl;
      avf[i] = *(const bf16x8*)&As[ra * 32 + ((kb ^ (ra & 3)) << 3)];
      int rb = wn + i * 16 + rl;
      bvf[i] = *(const bf16x8*)&Bs[rb * 32 + ((kb ^ (rb & 3)) << 3)];
    }
#pragma unroll
    for (int i = 0; i < 4; ++i)
#pragma unroll
      for (int j = 0; j < 4; ++j)
        acc[i][j] = __builtin_amdgcn_mfma_f32_16x16x32_bf16(avf[i], bvf[j],
                                                            acc[i][j], 0, 0, 0);
    __syncthreads();
  }

#pragma unroll
  for (int i = 0; i < 4; ++i) {
#pragma unroll
    for (int j = 0; j < 4; ++j) {
      int col = n0 + wn + j * 16 + rl;
      float bsv = bias[col];
#pragma unroll
      for (int r = 0; r < 4; ++r) {
        int row = m0 + wm + i * 16 + kb * 4 + r;
        size_t o = (size_t)row * Np + col;
        float v = acc[i][j][r] + bsv;
        if (EPI == 1) v += R[o];
        if (EPI == 2) v += ((const float*)Cv)[o];
        if (OUTBF16) ((__hip_bfloat16*)Cv)[o] = __float2bfloat16(v);
        else ((float*)Cv)[o] = v;
      }
    }
  }
}

// ---------------------------------------------------------------------------
// Deformable sampling. One wave per (b,n,head); lane = channel (64).
// value bf16 [B*NTOK][384]; offatt fp32 [T][256]: cols 0..143 offsets,
// 144..215 attn logits. Output samp bf16 [T][384].
// Tap addresses are wave-uniform -> readfirstlane to scalarize.
// ---------------------------------------------------------------------------
__global__ __launch_bounds__(256) void msdeform_sample(
    const __hip_bfloat16* __restrict__ value, const float* __restrict__ offatt,
    __hip_bfloat16* __restrict__ samp) {
  int wid = (blockIdx.x * blockDim.x + threadIdx.x) >> 6;
  if (wid >= TOKS * NHEADS) return;
  int lane = threadIdx.x & 63;
  int h = wid % NHEADS;
  int t = wid / NHEADS;
  int b = t / NTOK;
  int nq = t - b * NTOK;

  int pos, Hq, Wq;
  if (nq < 9216)       { pos = nq;         Hq = 96; Wq = 96; }
  else if (nq < 11520) { pos = nq - 9216;  Hq = 48; Wq = 48; }
  else                 { pos = nq - 11520; Hq = 24; Wq = 24; }
  int iq = pos / Wq, jq = pos - iq * Wq;
  float refx = (jq + 0.5f) / (float)Wq;
  float refy = (iq + 0.5f) / (float)Hq;

  const float* of = offatt + (size_t)t * 256 + h * 24;
  const float* lg = offatt + (size_t)t * 256 + 144 + h * 12;

  float e[12];
  float mx = -1e30f;
#pragma unroll
  for (int i = 0; i < 12; ++i) mx = fmaxf(mx, lg[i]);
  float sden = 0.f;
#pragma unroll
  for (int i = 0; i < 12; ++i) { e[i] = __expf(lg[i] - mx); sden += e[i]; }
  float inv = 1.f / sden;

  const __hip_bfloat16* vb = value + (size_t)b * NTOK * DIMC + h * CHD;

  const int Hls[3] = {96, 48, 24};
  const int Sts[3] = {0, 9216, 11520};

  float acc = 0.f;
#pragma unroll
  for (int l = 0; l < 3; ++l) {
    const int Wl = Hls[l], Hl = Hls[l], st = Sts[l];
#pragma unroll
    for (int p = 0; p < 4; ++p) {
      float ox = of[(l * 4 + p) * 2 + 0];
      float oy = of[(l * 4 + p) * 2 + 1];
      float xx = refx * (float)Wl + ox - 0.5f;
      float yy = refy * (float)Hl + oy - 0.5f;
      float x0f = floorf(xx), y0f = floorf(yy);
      int x0 = (int)x0f, y0 = (int)y0f;
      float wx = xx - x0f, wy = yy - y0f;
      float aw = e[l * 4 + p] * inv;

      bool vx0 = (x0 >= 0) & (x0 < Wl), vx1 = (x0 + 1 >= 0) & (x0 + 1 < Wl);
      bool vy0 = (y0 >= 0) & (y0 < Hl), vy1 = (y0 + 1 >= 0) & (y0 + 1 < Hl);
      int x0c = min(max(x0, 0), Wl - 1), x1c = min(max(x0 + 1, 0), Wl - 1);
      int y0c = min(max(y0, 0), Hl - 1), y1c = min(max(y0 + 1, 0), Hl - 1);

      float w00 = (vy0 && vx0) ? aw * (1.f - wx) * (1.f - wy) : 0.f;
      float w01 = (vy0 && vx1) ? aw * wx * (1.f - wy) : 0.f;
      float w10 = (vy1 && vx0) ? aw * (1.f - wx) * wy : 0.f;
      float w11 = (vy1 && vx1) ? aw * wx * wy : 0.f;

      int r0 = (st + y0c * Wl) * DIMC, r1 = (st + y1c * Wl) * DIMC;
      int i00 = __builtin_amdgcn_readfirstlane(r0 + x0c * DIMC);
      int i01 = __builtin_amdgcn_readfirstlane(r0 + x1c * DIMC);
      int i10 = __builtin_amdgcn_readfirstlane(r1 + x0c * DIMC);
      int i11 = __builtin_amdgcn_readfirstlane(r1 + x1c * DIMC);

      acc += w00 * __bfloat162float(vb[i00 + lane]);
      acc += w01 * __bfloat162float(vb[i01 + lane]);
      acc += w10 * __bfloat162float(vb[i10 + lane]);
      acc += w11 * __bfloat162float(vb[i11 + lane]);
    }
  }
  samp[(size_t)t * DIMC + h * CHD + lane] = __float2bfloat16(acc);
}

// ---------------------------------------------------------------------------
// Depthwise 3x3 + bias + exact GELU. x bf16 [T][128] (padded), y bf16 [T][96].
// ---------------------------------------------------------------------------
__global__ __launch_bounds__(256) void dwconv_gelu(
    const __hip_bfloat16* __restrict__ x, const float* __restrict__ w,
    const float* __restrict__ bias, __hip_bfloat16* __restrict__ y) {
  int id = blockIdx.x * blockDim.x + threadIdx.x;
  if (id >= TOKS * 96) return;
  int ch = id % 96;
  int tn = id / 96;
  int b = tn / NTOK, nq = tn - b * NTOK;

  int pos, Hl, Wl, st;
  if (nq < 9216)       { pos = nq;         Hl = 96; Wl = 96; st = 0; }
  else if (nq < 11520) { pos = nq - 9216;  Hl = 48; Wl = 48; st = 9216; }
  else                 { pos = nq - 11520; Hl = 24; Wl = 24; st = 11520; }
  int i = pos / Wl, j = pos - i * Wl;

  float acc = bias[ch];
#pragma unroll
  for (int di = 0; di < 3; ++di) {
#pragma unroll
    for (int dj = 0; dj < 3; ++dj) {
      int ii = i + di - 1, jj = j + dj - 1;
      if (ii >= 0 && ii < Hl && jj >= 0 && jj < Wl) {
        acc += __bfloat162float(
                   x[((size_t)(b * NTOK + st + ii * Wl + jj)) * 128 + ch]) *
               w[(di * 3 + dj) * 96 + ch];
      }
    }
  }
  float g = 0.5f * acc * (1.f + erff(acc * 0.70710678118654752440f));
  y[(size_t)tn * 96 + ch] = __float2bfloat16(g);
}

// ---------------------------------------------------------------------------
extern "C" void kernel_launch(void* const* d_in, const int* in_sizes, int n_in,
                              void* d_out, int out_size, void* d_ws, size_t ws_size,
                              hipStream_t stream) {
  const float* query = (const float*)d_in[0];
  const float* feat   = (const float*)d_in[2];
  const float* cti_qw = (const float*)d_in[7];
  const float* cti_qb = (const float*)d_in[8];
  const float* cti_fw = (const float*)d_in[9];
  const float* cti_fb = (const float*)d_in[10];
  const float* cf_qw  = (const float*)d_in[11];
  const float* cf_qb  = (const float*)d_in[12];
  const float* cf_fw  = (const float*)d_in[13];
  const float* cf_fb  = (const float*)d_in[14];
  const float* Wv     = (const float*)d_in[15];
  const float* bv     = (const float*)d_in[16];
  const float* Woff   = (const float*)d_in[17];
  const float* boff   = (const float*)d_in[18];
  const float* Watt   = (const float*)d_in[19];
  const float* batt   = (const float*)d_in[20];
  const float* Wo     = (const float*)d_in[21];
  const float* bo     = (const float*)d_in[22];
  const float* ffw    = (const float*)d_in[23];
  const float* ffb    = (const float*)d_in[24];
  const float* fc1w   = (const float*)d_in[25];
  const float* fc1b   = (const float*)d_in[26];
  const float* dww    = (const float*)d_in[27];
  const float* dwb    = (const float*)d_in[28];
  const float* fc2w   = (const float*)d_in[29];
  const float* fc2b   = (const float*)d_in[30];
  float* out = (float*)d_out;

  char* ws = (char*)d_ws;
  float* qn = (float*)ws;                                   // T*384 f32
  __hip_bfloat16* aq  = (__hip_bfloat16*)(ws + 37158912);   // T*384 bf16
  __hip_bfloat16* af  = (__hip_bfloat16*)(ws + 55738368);   // T*384 bf16
  __hip_bfloat16* val = (__hip_bfloat16*)(ws + 74317824);   // T*384 bf16
  float* offatt       = (float*)(ws + 92897280);            // T*256 f32
  char* wbase = ws + 117669888;
  __hip_bfloat16* Wvt   = (__hip_bfloat16*)(wbase + 0);
  __hip_bfloat16* Wot   = (__hip_bfloat16*)(wbase + 589824);
  __hip_bfloat16* Wofat = (__hip_bfloat16*)(wbase + 1179648);
  __hip_bfloat16* fc1t  = (__hip_bfloat16*)(wbase + 1376256);
  __hip_bfloat16* fc2t  = (__hip_bfloat16*)(wbase + 1474560);
  float* bofat          = (float*)(wbase + 1548288);
  float* fc1bp          = (float*)(wbase + 1549312);
  // reuse regions
  __hip_bfloat16* samp = af;
  __hip_bfloat16* lnf  = aq;
  __hip_bfloat16* h1   = (__hip_bfloat16*)offatt;           // T*128 bf16
  __hip_bfloat16* h2   = (__hip_bfloat16*)(ws + 92897280 + 6193152); // T*96 bf16

  dim3 blk(256);

  convert_weights<<<576, blk, 0, stream>>>(Wv, Woff, Watt, Wo, fc1w, fc2w, boff,
                                           batt, fc1b, Wvt, Wot, Wofat, fc1t,
                                           fc2t, bofat, fc1bp);

  fused_ln3<<<TOKS / 4, blk, 0, stream>>>(query, feat, cti_qw, cti_qb, cti_fw,
                                          cti_fb, cf_qw, cf_qb, cf_fw, cf_fb,
                                          qn, aq, af);

  // value = af @ Wv + bv  -> bf16 [T][384]
  gemm_mfma<0, 1><<<dim3(3, 189), blk, 0, stream>>>(af, Wvt, bv, nullptr, val, 384, 384);
  // offsets+logits = aq @ [Woff|Watt] -> f32 [T][256]
  gemm_mfma<0, 0><<<dim3(2, 189), blk, 0, stream>>>(aq, Wofat, bofat, nullptr, offatt, 384, 256);

  msdeform_sample<<<(TOKS * NHEADS) / 4, blk, 0, stream>>>(val, offatt, samp);

  // out = samp @ Wout + bout + qn  (f32)
  gemm_mfma<1, 0><<<dim3(3, 189), blk, 0, stream>>>(samp, Wot, bo, qn, out, 384, 384);

  ln_kernel<<<TOKS / 4, blk, 0, stream>>>(out, ffw, ffb, lnf);
  // h1 = lnf @ fc1 -> bf16 [T][128]
  gemm_mfma<0, 1><<<dim3(1, 189), blk, 0, stream>>>(lnf, fc1t, fc1bp, nullptr, h1, 384, 128);
  dwconv_gelu<<<(TOKS * 96) / 256, blk, 0, stream>>>(h1, dww, dwb, h2);
  // out += h2 @ fc2 + fc2_b  (K=96)
  gemm_mfma<2, 0><<<dim3(3, 189), blk, 0, stream>>>(h2, fc2t, fc2b, nullptr, out, 96, 384);
}

// Round 3
// 237.100 us; speedup vs baseline: 3.9800x; 1.7694x over previous
//
#include <hip/hip_runtime.h>
#include <hip/hip_bf16.h>
#include <hip/hip_fp16.h>
#include <cstdint>
#include <cstddef>

#define NB 2
#define NTOK 12096
#define TOKS (NB * NTOK)   // 24192
#define DIMC 384
#define NHEADS 6
#define CHD 64

typedef __attribute__((ext_vector_type(8))) __bf16 bf16x8;
typedef __attribute__((ext_vector_type(4))) float f32x4;

__device__ __forceinline__ float wave_reduce_add(float v) {
#pragma unroll
  for (int o = 32; o > 0; o >>= 1) v += __shfl_xor(v, o, 64);
  return v;
}

__device__ __forceinline__ float bf2f(ushort u) {
  union { uint i; float f; } c; c.i = (uint)u << 16; return c.f;
}
__device__ __forceinline__ uint f2toh2(float a, float b) {
  __half2 h; h.x = __float2half_rn(a); h.y = __float2half_rn(b);
  union { __half2 h2; uint u; } c; c.h2 = h; return c.u;
}
__device__ __forceinline__ float2 h2tof2(uint u) {
  union { uint uu; __half2 h2; } c; c.uu = u;
  return __half22float2(c.h2);
}

// ---------------------------------------------------------------------------
// Weight conversion: fp32 [K][N] -> bf16 transposed+padded [Np][K], plus
// concatenated/padded biases.
// ---------------------------------------------------------------------------
__global__ __launch_bounds__(256) void convert_weights(
    const float* __restrict__ Wv, const float* __restrict__ Woff,
    const float* __restrict__ Watt, const float* __restrict__ Wo,
    const float* __restrict__ fc1, const float* __restrict__ fc2,
    const float* __restrict__ boff, const float* __restrict__ batt,
    const float* __restrict__ fc1b,
    __hip_bfloat16* __restrict__ Wvt, __hip_bfloat16* __restrict__ Wot,
    __hip_bfloat16* __restrict__ Wofat, __hip_bfloat16* __restrict__ fc1t,
    __hip_bfloat16* __restrict__ fc2t, float* __restrict__ bofat,
    float* __restrict__ fc1bp) {
  int id = blockIdx.x * 256 + threadIdx.x;
  if (id >= 384 * 384) return;
  int k = id % 384, n = id / 384;
  Wvt[(size_t)n * 384 + k] = __float2bfloat16(Wv[(size_t)k * 384 + n]);
  Wot[(size_t)n * 384 + k] = __float2bfloat16(Wo[(size_t)k * 384 + n]);
  if (n < 256) {
    float v = 0.f;
    if (n < 144) v = Woff[(size_t)k * 144 + n];
    else if (n < 216) v = Watt[(size_t)k * 72 + (n - 144)];
    Wofat[(size_t)n * 384 + k] = __float2bfloat16(v);
  }
  if (n < 128)
    fc1t[(size_t)n * 384 + k] = __float2bfloat16(n < 96 ? fc1[(size_t)k * 96 + n] : 0.f);
  if (k < 96)
    fc2t[(size_t)n * 96 + k] = __float2bfloat16(fc2[(size_t)k * 384 + n]);
  if (id < 256) bofat[id] = id < 144 ? boff[id] : (id < 216 ? batt[id - 144] : 0.f);
  if (id < 128) fc1bp[id] = id < 96 ? fc1b[id] : 0.f;
}

// ---------------------------------------------------------------------------
// K1: q = query (+feat on middle level); qn = LN(q)*w1+b1 (fp32);
// aq = LN(qn)*w3+b3 (bf16); af = LN(LN(q)*w2+b2)*w4+b4 (bf16).
// ---------------------------------------------------------------------------
__global__ __launch_bounds__(256) void fused_ln3(
    const float* __restrict__ query, const float* __restrict__ feat,
    const float* __restrict__ w1, const float* __restrict__ b1,
    const float* __restrict__ w2, const float* __restrict__ b2,
    const float* __restrict__ w3, const float* __restrict__ b3,
    const float* __restrict__ w4, const float* __restrict__ b4,
    float* __restrict__ qn, __hip_bfloat16* __restrict__ aq,
    __hip_bfloat16* __restrict__ af) {
  int wid = (blockIdx.x * blockDim.x + threadIdx.x) >> 6;
  if (wid >= TOKS) return;
  int lane = threadIdx.x & 63;
  int bb = wid / NTOK;
  int nq = wid - bb * NTOK;

  float x[6];
  const float* qp = query + (size_t)wid * DIMC + lane;
#pragma unroll
  for (int i = 0; i < 6; ++i) x[i] = qp[64 * i];
  if (nq >= 9216 && nq < 11520) {
    const float* fp = feat + ((size_t)bb * 2304 + (nq - 9216)) * DIMC + lane;
#pragma unroll
    for (int i = 0; i < 6; ++i) x[i] += fp[64 * i];
  }

  float s = 0.f, ss = 0.f;
#pragma unroll
  for (int i = 0; i < 6; ++i) { s += x[i]; ss += x[i] * x[i]; }
  s = wave_reduce_add(s); ss = wave_reduce_add(ss);
  float mean = s * (1.f / DIMC);
  float rs = rsqrtf(ss * (1.f / DIMC) - mean * mean + 1e-6f);

  float qv[6], fv[6];
  float* qnp = qn + (size_t)wid * DIMC + lane;
#pragma unroll
  for (int i = 0; i < 6; ++i) {
    int e = lane + 64 * i;
    float xh = (x[i] - mean) * rs;
    qv[i] = xh * w1[e] + b1[e];
    fv[i] = xh * w2[e] + b2[e];
    qnp[64 * i] = qv[i];
  }

  s = 0.f; ss = 0.f;
#pragma unroll
  for (int i = 0; i < 6; ++i) { s += qv[i]; ss += qv[i] * qv[i]; }
  s = wave_reduce_add(s); ss = wave_reduce_add(ss);
  float m2 = s * (1.f / DIMC);
  float rs2 = rsqrtf(ss * (1.f / DIMC) - m2 * m2 + 1e-6f);
  __hip_bfloat16* aqp = aq + (size_t)wid * DIMC + lane;
#pragma unroll
  for (int i = 0; i < 6; ++i) {
    int e = lane + 64 * i;
    aqp[64 * i] = __float2bfloat16((qv[i] - m2) * rs2 * w3[e] + b3[e]);
  }

  s = 0.f; ss = 0.f;
#pragma unroll
  for (int i = 0; i < 6; ++i) { s += fv[i]; ss += fv[i] * fv[i]; }
  s = wave_reduce_add(s); ss = wave_reduce_add(ss);
  float m3 = s * (1.f / DIMC);
  float rs3 = rsqrtf(ss * (1.f / DIMC) - m3 * m3 + 1e-6f);
  __hip_bfloat16* afp = af + (size_t)wid * DIMC + lane;
#pragma unroll
  for (int i = 0; i < 6; ++i) {
    int e = lane + 64 * i;
    afp[64 * i] = __float2bfloat16((fv[i] - m3) * rs3 * w4[e] + b4[e]);
  }
}

// ---------------------------------------------------------------------------
// ffn_norm: fp32 in -> bf16 out
// ---------------------------------------------------------------------------
__global__ __launch_bounds__(256) void ln_kernel(
    const float* __restrict__ x, const float* __restrict__ w,
    const float* __restrict__ b, __hip_bfloat16* __restrict__ y) {
  int wid = (blockIdx.x * blockDim.x + threadIdx.x) >> 6;
  if (wid >= TOKS) return;
  int lane = threadIdx.x & 63;
  float v[6];
  const float* xp = x + (size_t)wid * DIMC + lane;
#pragma unroll
  for (int i = 0; i < 6; ++i) v[i] = xp[64 * i];
  float s = 0.f, ss = 0.f;
#pragma unroll
  for (int i = 0; i < 6; ++i) { s += v[i]; ss += v[i] * v[i]; }
  s = wave_reduce_add(s); ss = wave_reduce_add(ss);
  float mean = s * (1.f / DIMC);
  float rs = rsqrtf(ss * (1.f / DIMC) - mean * mean + 1e-6f);
  __hip_bfloat16* yp = y + (size_t)wid * DIMC + lane;
#pragma unroll
  for (int i = 0; i < 6; ++i) {
    int e = lane + 64 * i;
    yp[64 * i] = __float2bfloat16((v[i] - mean) * rs * w[e] + b[e]);
  }
}

// ---------------------------------------------------------------------------
// bf16 MFMA GEMM: C[M x Np] = A[M x K](bf16) @ Wt[Np x K](bf16, transposed)
// 128x128 tile, 4 waves (2x2), each wave 64x64 = 4x4 16x16x32 fragments.
// ---------------------------------------------------------------------------
template <int EPI, int OUTBF16>
__global__ __launch_bounds__(256) void gemm_mfma(
    const __hip_bfloat16* __restrict__ A, const __hip_bfloat16* __restrict__ Wt,
    const float* __restrict__ bias, const float* __restrict__ R,
    void* __restrict__ Cv, int K, int Np) {
  __shared__ __align__(16) ushort As[128 * 32];
  __shared__ __align__(16) ushort Bs[128 * 32];
  const int tid = threadIdx.x;
  const int m0 = blockIdx.y * 128, n0 = blockIdx.x * 128;
  const int lane = tid & 63, wid = tid >> 6;
  const int wm = (wid >> 1) * 64, wn = (wid & 1) * 64;
  const int srow = tid >> 2, skb = tid & 3;
  const int rl = lane & 15, kb = lane >> 4;
  f32x4 acc[4][4] = {};

  for (int k0 = 0; k0 < K; k0 += 32) {
#pragma unroll
    for (int hh = 0; hh < 2; ++hh) {
      int r = srow + hh * 64;
      const ushort* ga = (const ushort*)A + (size_t)(m0 + r) * K + k0 + skb * 8;
      const ushort* gb = (const ushort*)Wt + (size_t)(n0 + r) * K + k0 + skb * 8;
      *(bf16x8*)&As[r * 32 + ((skb ^ (r & 3)) << 3)] = *(const bf16x8*)ga;
      *(bf16x8*)&Bs[r * 32 + ((skb ^ (r & 3)) << 3)] = *(const bf16x8*)gb;
    }
    __syncthreads();
    bf16x8 avf[4], bvf[4];
#pragma unroll
    for (int i = 0; i < 4; ++i) {
      int ra = wm + i * 16 + rl;
      avf[i] = *(const bf16x8*)&As[ra * 32 + ((kb ^ (ra & 3)) << 3)];
      int rb = wn + i * 16 + rl;
      bvf[i] = *(const bf16x8*)&Bs[rb * 32 + ((kb ^ (rb & 3)) << 3)];
    }
#pragma unroll
    for (int i = 0; i < 4; ++i)
#pragma unroll
      for (int j = 0; j < 4; ++j)
        acc[i][j] = __builtin_amdgcn_mfma_f32_16x16x32_bf16(avf[i], bvf[j],
                                                            acc[i][j], 0, 0, 0);
    __syncthreads();
  }

#pragma unroll
  for (int i = 0; i < 4; ++i) {
#pragma unroll
    for (int j = 0; j < 4; ++j) {
      int col = n0 + wn + j * 16 + rl;
      float bsv = bias[col];
#pragma unroll
      for (int r = 0; r < 4; ++r) {
        int row = m0 + wm + i * 16 + kb * 4 + r;
        size_t o = (size_t)row * Np + col;
        float v = acc[i][j][r] + bsv;
        if (EPI == 1) v += R[o];
        if (EPI == 2) v += ((const float*)Cv)[o];
        if (OUTBF16) ((__hip_bfloat16*)Cv)[o] = __float2bfloat16(v);
        else ((float*)Cv)[o] = v;
      }
    }
  }
}

// ---------------------------------------------------------------------------
// Sampling phase 1: one THREAD per (t, h, l, p). Computes softmax weight,
// 4 bilinear tap weights (f16) and 4 clamped byte-offset indices into value.
// Lane-parallelizes the formerly wave-uniform float math.
// ---------------------------------------------------------------------------
__global__ __launch_bounds__(256) void msdeform_prep(
    const float* __restrict__ offatt, int4* __restrict__ twi,
    uint* __restrict__ tww) {
  int id = blockIdx.x * 256 + threadIdx.x;
  if (id >= TOKS * 72) return;
  int t = id / 72, r = id - t * 72;
  int h = r / 12, lp = r - h * 12;
  int l = lp >> 2;
  int b = t / NTOK, nq = t - b * NTOK;

  // reference point from the query's own level grid
  int pos, Hq, Wq;
  if (nq < 9216)       { pos = nq;         Hq = 96; Wq = 96; }
  else if (nq < 11520) { pos = nq - 9216;  Hq = 48; Wq = 48; }
  else                 { pos = nq - 11520; Hq = 24; Wq = 24; }
  int iq = pos / Wq, jq = pos - iq * Wq;
  float refx = (jq + 0.5f) / (float)Wq;
  float refy = (iq + 0.5f) / (float)Hq;

  // softmax over this head's 12 logits (lane-parallel, redundant x12)
  const float* lg = offatt + (size_t)t * 256 + 144 + h * 12;
  float mx = -1e30f;
#pragma unroll
  for (int i = 0; i < 12; ++i) mx = fmaxf(mx, lg[i]);
  float sden = 0.f;
#pragma unroll
  for (int i = 0; i < 12; ++i) sden += __expf(lg[i] - mx);
  float aw = __expf(lg[lp] - mx) / sden;

  // this point's offset
  float ox = offatt[(size_t)t * 256 + h * 24 + lp * 2 + 0];
  float oy = offatt[(size_t)t * 256 + h * 24 + lp * 2 + 1];

  int Wl = 96 >> l;
  int st = (l == 0) ? 0 : ((l == 1) ? 9216 : 11520);

  float xx = refx * (float)Wl + ox - 0.5f;
  float yy = refy * (float)Wl + oy - 0.5f;
  float x0f = floorf(xx), y0f = floorf(yy);
  int x0 = (int)x0f, y0 = (int)y0f;
  float wx = xx - x0f, wy = yy - y0f;

  bool vx0 = (x0 >= 0) & (x0 < Wl), vx1 = (x0 + 1 >= 0) & (x0 + 1 < Wl);
  bool vy0 = (y0 >= 0) & (y0 < Wl), vy1 = (y0 + 1 >= 0) & (y0 + 1 < Wl);
  int x0c = min(max(x0, 0), Wl - 1), x1c = min(max(x0 + 1, 0), Wl - 1);
  int y0c = min(max(y0, 0), Wl - 1), y1c = min(max(y0 + 1, 0), Wl - 1);

  float w00 = (vy0 && vx0) ? aw * (1.f - wx) * (1.f - wy) : 0.f;
  float w01 = (vy0 && vx1) ? aw * wx * (1.f - wy) : 0.f;
  float w10 = (vy1 && vx0) ? aw * (1.f - wx) * wy : 0.f;
  float w11 = (vy1 && vx1) ? aw * wx * wy : 0.f;

  // byte offsets into value (bf16 [B*NTOK][384]), channel base h*64
  int base = (b * NTOK + st) * DIMC + h * CHD;
  int r0 = (base + y0c * Wl * DIMC) * 2, r1 = (base + y1c * Wl * DIMC) * 2;
  int4 idx;
  idx.x = r0 + x0c * DIMC * 2;
  idx.y = r0 + x1c * DIMC * 2;
  idx.z = r1 + x0c * DIMC * 2;
  idx.w = r1 + x1c * DIMC * 2;
  twi[id] = idx;
  tww[id * 2 + 0] = f2toh2(w00, w01);
  tww[id * 2 + 1] = f2toh2(w10, w11);
}

// ---------------------------------------------------------------------------
// Sampling phase 2: one wave per (t,h); lane = channel. All (idx,w) loads are
// wave-uniform (scalarized via readfirstlane'd wid) -> per tap just
// v_add + global_load_ushort + cvt + fma.
// ---------------------------------------------------------------------------
__global__ __launch_bounds__(256) void msdeform_gather(
    const __hip_bfloat16* __restrict__ value, const int4* __restrict__ twi,
    const uint* __restrict__ tww, __hip_bfloat16* __restrict__ samp) {
  int wid0 = (blockIdx.x * 256 + threadIdx.x) >> 6;
  int wid = __builtin_amdgcn_readfirstlane(wid0);
  int lane = threadIdx.x & 63;
  const char* vb = (const char*)value;
  int vl2 = lane * 2;

  float acc0 = 0.f, acc1 = 0.f;
#pragma unroll
  for (int i = 0; i < 12; ++i) {
    int4 idx = twi[wid * 12 + i];
    uint2 wp = *(const uint2*)&tww[(wid * 12 + i) * 2];
    float2 wa = h2tof2(wp.x);
    float2 wb = h2tof2(wp.y);
    ushort r00 = *(const ushort*)(vb + idx.x + vl2);
    ushort r01 = *(const ushort*)(vb + idx.y + vl2);
    ushort r10 = *(const ushort*)(vb + idx.z + vl2);
    ushort r11 = *(const ushort*)(vb + idx.w + vl2);
    acc0 += wa.x * bf2f(r00);
    acc1 += wa.y * bf2f(r01);
    acc0 += wb.x * bf2f(r10);
    acc1 += wb.y * bf2f(r11);
  }
  samp[(size_t)wid * 64 + lane] = __float2bfloat16(acc0 + acc1);
}

// ---------------------------------------------------------------------------
// Depthwise 3x3 + bias + exact GELU. x bf16 [T][128] (padded), y bf16 [T][96].
// ---------------------------------------------------------------------------
__global__ __launch_bounds__(256) void dwconv_gelu(
    const __hip_bfloat16* __restrict__ x, const float* __restrict__ w,
    const float* __restrict__ bias, __hip_bfloat16* __restrict__ y) {
  int id = blockIdx.x * blockDim.x + threadIdx.x;
  if (id >= TOKS * 96) return;
  int ch = id % 96;
  int tn = id / 96;
  int b = tn / NTOK, nq = tn - b * NTOK;

  int pos, Hl, Wl, st;
  if (nq < 9216)       { pos = nq;         Hl = 96; Wl = 96; st = 0; }
  else if (nq < 11520) { pos = nq - 9216;  Hl = 48; Wl = 48; st = 9216; }
  else                 { pos = nq - 11520; Hl = 24; Wl = 24; st = 11520; }
  int i = pos / Wl, j = pos - i * Wl;

  float acc = bias[ch];
#pragma unroll
  for (int di = 0; di < 3; ++di) {
#pragma unroll
    for (int dj = 0; dj < 3; ++dj) {
      int ii = i + di - 1, jj = j + dj - 1;
      if (ii >= 0 && ii < Hl && jj >= 0 && jj < Wl) {
        acc += __bfloat162float(
                   x[((size_t)(b * NTOK + st + ii * Wl + jj)) * 128 + ch]) *
               w[(di * 3 + dj) * 96 + ch];
      }
    }
  }
  float g = 0.5f * acc * (1.f + erff(acc * 0.70710678118654752440f));
  y[(size_t)tn * 96 + ch] = __float2bfloat16(g);
}

// ---------------------------------------------------------------------------
extern "C" void kernel_launch(void* const* d_in, const int* in_sizes, int n_in,
                              void* d_out, int out_size, void* d_ws, size_t ws_size,
                              hipStream_t stream) {
  const float* query = (const float*)d_in[0];
  const float* feat   = (const float*)d_in[2];
  const float* cti_qw = (const float*)d_in[7];
  const float* cti_qb = (const float*)d_in[8];
  const float* cti_fw = (const float*)d_in[9];
  const float* cti_fb = (const float*)d_in[10];
  const float* cf_qw  = (const float*)d_in[11];
  const float* cf_qb  = (const float*)d_in[12];
  const float* cf_fw  = (const float*)d_in[13];
  const float* cf_fb  = (const float*)d_in[14];
  const float* Wv     = (const float*)d_in[15];
  const float* bv     = (const float*)d_in[16];
  const float* Woff   = (const float*)d_in[17];
  const float* boff   = (const float*)d_in[18];
  const float* Watt   = (const float*)d_in[19];
  const float* batt   = (const float*)d_in[20];
  const float* Wo     = (const float*)d_in[21];
  const float* bo     = (const float*)d_in[22];
  const float* ffw    = (const float*)d_in[23];
  const float* ffb    = (const float*)d_in[24];
  const float* fc1w   = (const float*)d_in[25];
  const float* fc1b   = (const float*)d_in[26];
  const float* dww    = (const float*)d_in[27];
  const float* dwb    = (const float*)d_in[28];
  const float* fc2w   = (const float*)d_in[29];
  const float* fc2b   = (const float*)d_in[30];
  float* out = (float*)d_out;

  char* ws = (char*)d_ws;
  float* qn = (float*)ws;                                   // T*384 f32
  __hip_bfloat16* aq  = (__hip_bfloat16*)(ws + 37158912);   // T*384 bf16
  __hip_bfloat16* af  = (__hip_bfloat16*)(ws + 55738368);   // T*384 bf16
  __hip_bfloat16* val = (__hip_bfloat16*)(ws + 74317824);   // T*384 bf16
  float* offatt       = (float*)(ws + 92897280);            // T*256 f32
  char* wbase = ws + 117669888;
  __hip_bfloat16* Wvt   = (__hip_bfloat16*)(wbase + 0);
  __hip_bfloat16* Wot   = (__hip_bfloat16*)(wbase + 589824);
  __hip_bfloat16* Wofat = (__hip_bfloat16*)(wbase + 1179648);
  __hip_bfloat16* fc1t  = (__hip_bfloat16*)(wbase + 1376256);
  __hip_bfloat16* fc2t  = (__hip_bfloat16*)(wbase + 1474560);
  float* bofat          = (float*)(wbase + 1548288);
  float* fc1bp          = (float*)(wbase + 1549312);
  // sampling tap tables (twi in tail; tww overlays dead aq region)
  int4* twi = (int4*)(ws + 119220224);                      // T*72*16 = 27.9MB
  uint* tww = (uint*)aq;                                    // T*72*8  = 13.9MB
  // reuse regions
  __hip_bfloat16* samp = af;
  __hip_bfloat16* lnf  = aq;
  __hip_bfloat16* h1   = (__hip_bfloat16*)offatt;           // T*128 bf16
  __hip_bfloat16* h2   = (__hip_bfloat16*)(ws + 92897280 + 6193152); // T*96 bf16

  dim3 blk(256);

  convert_weights<<<576, blk, 0, stream>>>(Wv, Woff, Watt, Wo, fc1w, fc2w, boff,
                                           batt, fc1b, Wvt, Wot, Wofat, fc1t,
                                           fc2t, bofat, fc1bp);

  fused_ln3<<<TOKS / 4, blk, 0, stream>>>(query, feat, cti_qw, cti_qb, cti_fw,
                                          cti_fb, cf_qw, cf_qb, cf_fw, cf_fb,
                                          qn, aq, af);

  // value = af @ Wv + bv  -> bf16 [T][384]
  gemm_mfma<0, 1><<<dim3(3, 189), blk, 0, stream>>>(af, Wvt, bv, nullptr, val, 384, 384);
  // offsets+logits = aq @ [Woff|Watt] -> f32 [T][256]
  gemm_mfma<0, 0><<<dim3(2, 189), blk, 0, stream>>>(aq, Wofat, bofat, nullptr, offatt, 384, 256);

  // sampling: lane-parallel prep, then slim gather
  msdeform_prep<<<(TOKS * 72) / 256, blk, 0, stream>>>(offatt, twi, tww);
  msdeform_gather<<<(TOKS * NHEADS) / 4, blk, 0, stream>>>(val, twi, tww, samp);

  // out = samp @ Wout + bout + qn  (f32)
  gemm_mfma<1, 0><<<dim3(3, 189), blk, 0, stream>>>(samp, Wot, bo, qn, out, 384, 384);

  ln_kernel<<<TOKS / 4, blk, 0, stream>>>(out, ffw, ffb, lnf);
  // h1 = lnf @ fc1 -> bf16 [T][128]
  gemm_mfma<0, 1><<<dim3(1, 189), blk, 0, stream>>>(lnf, fc1t, fc1bp, nullptr, h1, 384, 128);
  dwconv_gelu<<<(TOKS * 96) / 256, blk, 0, stream>>>(h1, dww, dwb, h2);
  // out += h2 @ fc2 + fc2_b  (K=96)
  gemm_mfma<2, 0><<<dim3(3, 189), blk, 0, stream>>>(h2, fc2t, fc2b, nullptr, out, 96, 384);
}